// Round 5
// baseline (955.920 us; speedup 1.0000x reference)
//
#include <hip/hip_runtime.h>
#include <cstdint>
#include <cstddef>

#pragma clang diagnostic ignored "-Waddress-space-conversion"

constexpr int T  = 16;
constexpr int N  = 10000;
constexpr int M  = 2048;
constexpr int F  = 256;
constexpr int H  = 256;
constexpr int G4 = 1024;
constexpr int NP = 10112;   // N padded to multiple of 128

typedef _Float16 f16;
using half8  = __attribute__((ext_vector_type(8))) f16;
using half4  = __attribute__((ext_vector_type(4))) f16;
using f32x4  = __attribute__((ext_vector_type(4))) float;

typedef __attribute__((address_space(1))) const void gas_t;
typedef __attribute__((address_space(3))) void las_t;

__device__ __forceinline__ void gl_lds16(const f16* g, f16* l) {
    __builtin_amdgcn_global_load_lds((gas_t*)g, (las_t*)l, 16, 0, 0);
}

// ---------------------------------------------------------------------------
// Generic MFMA GEMM: C[m][n] (+bias[n]) (+relu) = A[m][k] * B[n][k]
// AF32: A is fp32 (reg-staged + converted to f16 LDS); else f16 via global_load_lds.
// OMODE: 1 = f16 row-major, 2 = f16 transposed (C^T [Nn][ldct])
// SWAP:  m-tile on blockIdx.x, n-tile on blockIdx.y (XCD-locality for shared A panels)
// 128x128 tile, 4 waves, BK=32, double-buffered LDS.
// ---------------------------------------------------------------------------
template<bool AF32, bool RELU, int OMODE, bool SWAP>
__global__ __launch_bounds__(256, 3)
void gemm16(const void* __restrict__ Ag, long long sA,
            const f16*  __restrict__ Bg, long long sB,
            void*       __restrict__ Cg, long long sC,
            int Kk, int Nn, int Mvalid, int ldct,
            const float* __restrict__ bias)
{
    __shared__ f16 Als[2][128 * 32];
    __shared__ f16 Bls[2][128 * 32];

    const int tid  = threadIdx.x;
    const int lane = tid & 63;
    const int w    = tid >> 6;
    const int wm   = w >> 1, wn = w & 1;
    const int m0   = (SWAP ? blockIdx.x : blockIdx.y) * 128;
    const int n0   = (SWAP ? blockIdx.y : blockIdx.x) * 128;
    const int z    = blockIdx.z;

    const f16* Bt = Bg + (size_t)z * sB;
    const int srow = lane >> 2;
    const int scol = (lane & 3) * 8;

    f32x4 acc[4][4] = {};

    auto stage = [&](int buf, int kt) {
        const int k0 = kt * 32;
        #pragma unroll
        for (int c = 0; c < 2; ++c) {
            const int brow = w * 32 + c * 16;
            gl_lds16(Bt + (size_t)(n0 + brow + srow) * Kk + k0 + scol,
                     &Bls[buf][brow * 32]);
        }
        if constexpr (AF32) {
            const float* Af = (const float*)Ag + (size_t)z * sA;
            #pragma unroll
            for (int p = 0; p < 4; ++p) {
                const int flat = p * 1024 + tid * 4;
                const int r = flat >> 5, cc = flat & 31;
                float4 v = *(const float4*)&Af[(size_t)(m0 + r) * Kk + k0 + cc];
                half4 hv = { (f16)v.x, (f16)v.y, (f16)v.z, (f16)v.w };
                *(half4*)&Als[buf][r * 32 + cc] = hv;
            }
        } else {
            const f16* Af = (const f16*)Ag + (size_t)z * sA;
            #pragma unroll
            for (int c = 0; c < 2; ++c) {
                const int arow = w * 32 + c * 16;
                gl_lds16(Af + (size_t)(m0 + arow + srow) * Kk + k0 + scol,
                         &Als[buf][arow * 32]);
            }
        }
    };

    const int nk = Kk >> 5;
    stage(0, 0);
    int cur = 0;
    const int fr = lane & 15, fg = lane >> 4;

    for (int kt = 0; kt < nk; ++kt) {
        __syncthreads();
        if (kt + 1 < nk) stage(cur ^ 1, kt + 1);

        half8 a[4], b[4];
        #pragma unroll
        for (int i = 0; i < 4; ++i)
            a[i] = *(const half8*)&Als[cur][(wm * 64 + i * 16 + fr) * 32 + fg * 8];
        #pragma unroll
        for (int j = 0; j < 4; ++j)
            b[j] = *(const half8*)&Bls[cur][(wn * 64 + j * 16 + fr) * 32 + fg * 8];
        #pragma unroll
        for (int i = 0; i < 4; ++i)
            #pragma unroll
            for (int j = 0; j < 4; ++j)
                acc[i][j] = __builtin_amdgcn_mfma_f32_16x16x32_f16(a[i], b[j], acc[i][j], 0, 0, 0);
        cur ^= 1;
    }

    #pragma unroll
    for (int j = 0; j < 4; ++j) {
        const int gn = n0 + wn * 64 + j * 16 + fr;
        const float bb = bias ? bias[gn] : 0.f;
        #pragma unroll
        for (int i = 0; i < 4; ++i) {
            const int gmb = m0 + wm * 64 + i * 16 + fg * 4;
            f32x4 v = acc[i][j];
            #pragma unroll
            for (int r = 0; r < 4; ++r) {
                v[r] += bb;
                if (RELU) v[r] = fmaxf(v[r], 0.f);
            }
            if constexpr (OMODE == 1) {
                f16* Ch = (f16*)Cg + (size_t)z * sC;
                #pragma unroll
                for (int r = 0; r < 4; ++r)
                    if (gmb + r < Mvalid) Ch[(size_t)(gmb + r) * Nn + gn] = (f16)v[r];
            } else {
                f16* Ct = (f16*)Cg + (size_t)z * sC;
                half4 hv = { (f16)v[0], (f16)v[1], (f16)v[2], (f16)v[3] };
                if (gmb + 3 < Mvalid) *(half4*)&Ct[(size_t)gn * ldct + gmb] = hv;
            }
        }
    }
}

// ---------------------------------------------------------------------------
// Fused recurrent step (bias pre-folded into U/V; c-state in f16).
// Gate-interleaved permuted layout: fragment j == gate j of ONE unit.
// ---------------------------------------------------------------------------
__global__ __launch_bounds__(256, 3)
void gemm_lstm(const f16* __restrict__ h16, const f16* __restrict__ Whh,
               const f16* __restrict__ U, const f16* __restrict__ V,
               const int* __restrict__ invt,
               f16* __restrict__ Cb, f16* __restrict__ h16_out,
               float* __restrict__ hout)
{
    __shared__ f16 Als[2][128 * 32];
    __shared__ f16 Bls[2][128 * 32];

    const int tid  = threadIdx.x;
    const int lane = tid & 63;
    const int w    = tid >> 6;
    const int wm   = w >> 1, wn = w & 1;
    const int m0   = blockIdx.y * 128, n0 = blockIdx.x * 128;

    const int srow = lane >> 2;
    const int scol = (lane & 3) * 8;

    f32x4 acc[4][4] = {};

    auto stage = [&](int buf, int kt) {
        const int k0 = kt * 32;
        #pragma unroll
        for (int c = 0; c < 2; ++c) {
            const int row = w * 32 + c * 16;
            gl_lds16(Whh + (size_t)(n0 + row + srow) * H + k0 + scol, &Bls[buf][row * 32]);
            gl_lds16(h16 + (size_t)(m0 + row + srow) * H + k0 + scol, &Als[buf][row * 32]);
        }
    };

    stage(0, 0);
    int cur = 0;
    const int fr = lane & 15, fg = lane >> 4;

    for (int kt = 0; kt < H / 32; ++kt) {
        __syncthreads();
        if (kt + 1 < H / 32) stage(cur ^ 1, kt + 1);
        half8 a[4], b[4];
        #pragma unroll
        for (int i = 0; i < 4; ++i)
            a[i] = *(const half8*)&Als[cur][(wm * 64 + i * 16 + fr) * 32 + fg * 8];
        #pragma unroll
        for (int j = 0; j < 4; ++j)
            b[j] = *(const half8*)&Bls[cur][(wn * 64 + j * 16 + fr) * 32 + fg * 8];
        #pragma unroll
        for (int i = 0; i < 4; ++i)
            #pragma unroll
            for (int j = 0; j < 4; ++j)
                acc[i][j] = __builtin_amdgcn_mfma_f32_16x16x32_f16(a[i], b[j], acc[i][j], 0, 0, 0);
        cur ^= 1;
    }

    const int u = ((n0 >> 6) + wn) * 16 + fr;
    const int colbase = n0 + wn * 64 + fr;
    auto sig = [](float x) { return 1.f / (1.f + __expf(-x)); };

    #pragma unroll
    for (int i = 0; i < 4; ++i) {
        const int nodeb = m0 + wm * 64 + i * 16 + fg * 4;
        #pragma unroll
        for (int r = 0; r < 4; ++r) {
            const int node = nodeb + r;
            if (node >= N) continue;
            const int p = invt[node];
            const f16* xb = (p >= 0) ? V + (size_t)p * G4 : U + (size_t)node * G4;
            const float zi = acc[i][0][r] + (float)xb[colbase];
            const float zf = acc[i][1][r] + (float)xb[colbase + 16];
            const float zg = acc[i][2][r] + (float)xb[colbase + 32];
            const float zo = acc[i][3][r] + (float)xb[colbase + 48];
            const size_t ci = (size_t)node * H + u;
            const float c = sig(zf) * (float)Cb[ci] + sig(zi) * tanhf(zg);
            Cb[ci] = (f16)c;
            const float hv = sig(zo) * tanhf(c);
            h16_out[ci] = (f16)hv;
            if (hout) hout[ci] = hv;
        }
    }
}

// GT[t][f][p] = Y0h[mask[t][p]][f]
__global__ __launch_bounds__(256)
void gather_T(const f16* __restrict__ Y0h, const int* __restrict__ mask,
              f16* __restrict__ GT)
{
    __shared__ f16 tile[64][F + 8];
    const int t = blockIdx.y, p0 = blockIdx.x * 64;
    const int tid = threadIdx.x;
    const int pr = tid >> 2;
    const int fc = (tid & 3) * 8;

    const int row = mask[t * M + p0 + pr];
    const f16* src = Y0h + (size_t)row * F;
    #pragma unroll
    for (int it = 0; it < 8; ++it) {
        const int f = it * 32 + fc;
        *(half8*)&tile[pr][f] = *(const half8*)&src[f];
    }
    __syncthreads();

    f16* dst = GT + ((size_t)t * F + tid) * M + p0;
    #pragma unroll
    for (int pc = 0; pc < 64; pc += 8) {
        half8 v;
        #pragma unroll
        for (int r = 0; r < 8; ++r) v[r] = tile[pc + r][tid];
        *(half8*)&dst[pc] = v;
    }
}

__global__ void cvt_f16(const float* __restrict__ s, f16* __restrict__ d, long long n)
{
    long long base = ((long long)blockIdx.x * blockDim.x + threadIdx.x) * 4;
    if (base + 3 < n) {
        float4 v = *(const float4*)&s[base];
        half4 hv = { (f16)v.x, (f16)v.y, (f16)v.z, (f16)v.w };
        *(half4*)&d[base] = hv;
    } else {
        for (long long k = base; k < n; ++k) d[k] = (f16)s[k];
    }
}

__global__ void cvtT_f16(const float* __restrict__ s, f16* __restrict__ d, int R, int C)
{
    int i = blockIdx.x * 256 + threadIdx.x;
    if (i >= R * C) return;
    int r = i % R, c = i / R;
    d[(size_t)c * R + r] = (f16)s[(size_t)r * C + c];
}

// Wperm[pcol][k] = W[gate*256 + c64*16 + r][k], pcol = c64*64 + gate*16 + r
__global__ void permW(const float* __restrict__ s, f16* __restrict__ d, int K)
{
    const int pcol = blockIdx.x;
    const int c64 = pcol >> 6, within = pcol & 63, gate = within >> 4, r = within & 15;
    const int srow = gate * 256 + c64 * 16 + r;
    const float* sp = s + (size_t)srow * K;
    f16* dp = d + (size_t)pcol * K;
    const int k = threadIdx.x * 4;
    float4 v = *(const float4*)&sp[k];
    half4 hv = { (f16)v.x, (f16)v.y, (f16)v.z, (f16)v.w };
    *(half4*)&dp[k] = hv;
}

__global__ void bias_perm(const float* __restrict__ bi, const float* __restrict__ bh,
                          float* __restrict__ bsum)
{
    const int pcol = blockIdx.x * 256 + threadIdx.x;
    if (pcol >= G4) return;
    const int c64 = pcol >> 6, within = pcol & 63, gate = within >> 4, r = within & 15;
    const int srow = gate * 256 + c64 * 16 + r;
    bsum[pcol] = bi[srow] + bh[srow];
}

__global__ void build_inv(const int* __restrict__ mask, int* __restrict__ inv)
{
    int i = blockIdx.x * blockDim.x + threadIdx.x;
    if (i >= T * M) return;
    int t = i / M;
    inv[(size_t)t * N + mask[i]] = i % M;
}

extern "C" void kernel_launch(void* const* d_in, const int* in_sizes, int n_in,
                              void* d_out, int out_size, void* d_ws, size_t ws_size,
                              hipStream_t stream)
{
    const float* A_all = (const float*)d_in[0];
    const float* nf    = (const float*)d_in[1];
    const int*   mask  = (const int*)  d_in[2];
    const float* w0    = (const float*)d_in[3];
    const float* w1    = (const float*)d_in[4];
    const float* W_ih  = (const float*)d_in[5];
    const float* W_hh  = (const float*)d_in[6];
    const float* b_ih  = (const float*)d_in[7];
    const float* b_hh  = (const float*)d_in[8];
    float* h = (float*)d_out;

    char* wp = (char*)d_ws;
    auto alloc = [&](size_t bytes) { char* p = wp; wp += (bytes + 255) & ~(size_t)255; return p; };
    f16*   nf16  = (f16*)alloc((size_t)NP * F * 2);
    f16*   w0T   = (f16*)alloc((size_t)F * F * 2);
    f16*   w1T   = (f16*)alloc((size_t)F * F * 2);
    f16*   Wih16 = (f16*)alloc((size_t)G4 * F * 2);   // permuted rows
    f16*   Whh16 = (f16*)alloc((size_t)G4 * H * 2);   // permuted rows
    float* bsum  = (float*)alloc((size_t)G4 * 4);
    f16*   Y0h   = (f16*)alloc((size_t)NP * F * 2);
    f16*   Y1h   = (f16*)alloc((size_t)NP * F * 2);
    f16*   Uh    = (f16*)alloc((size_t)NP * G4 * 2);  // permuted cols, bias folded
    f16*   GT    = (f16*)alloc((size_t)T * F * M * 2);
    f16*   Z1b   = (f16*)alloc((size_t)T * M * F * 2);
    f16*   Z2T   = (f16*)alloc((size_t)T * F * M * 2);
    f16*   Z3b   = (f16*)alloc((size_t)T * M * F * 2);
    f16*   Vb    = (f16*)alloc((size_t)T * M * G4 * 2);  // all 16 steps
    f16*   Cb    = (f16*)alloc((size_t)N * H * 2);
    f16*   h16   = (f16*)alloc((size_t)NP * H * 2);
    int*   inv   = (int*)alloc((size_t)T * N * 4);

    hipMemsetAsync(Cb,  0,    (size_t)N * H * 2,  stream);
    hipMemsetAsync(h16, 0,    (size_t)NP * H * 2, stream);
    hipMemsetAsync(nf16,0,    (size_t)NP * F * 2, stream);
    hipMemsetAsync(inv, 0xFF, (size_t)T * N * 4,  stream);

    build_inv<<<(T * M + 255) / 256, 256, 0, stream>>>(mask, inv);
    cvt_f16 <<<((long long)N * F / 4 + 255) / 256, 256, 0, stream>>>(nf, nf16, (long long)N * F);
    cvtT_f16<<<(F * F + 255) / 256, 256, 0, stream>>>(w0, w0T, F, F);
    cvtT_f16<<<(F * F + 255) / 256, 256, 0, stream>>>(w1, w1T, F, F);
    permW<<<G4, 64, 0, stream>>>(W_ih, Wih16, F);
    permW<<<G4, 64, 0, stream>>>(W_hh, Whh16, H);
    bias_perm<<<(G4 + 255) / 256, 256, 0, stream>>>(b_ih, b_hh, bsum);

    gemm16<false,false,1,false><<<dim3(F / 128,  NP / 128, 1), 256, 0, stream>>>(nf16, 0, w0T,   0, Y0h, 0, F, F,  NP, 0, nullptr);
    gemm16<false,false,1,false><<<dim3(F / 128,  NP / 128, 1), 256, 0, stream>>>(Y0h,  0, w1T,   0, Y1h, 0, F, F,  NP, 0, nullptr);
    gemm16<false,false,1,false><<<dim3(G4 / 128, NP / 128, 1), 256, 0, stream>>>(Y1h,  0, Wih16, 0, Uh,  0, F, G4, NP, 0, bsum);

    gather_T<<<dim3(M / 64, T), 256, 0, stream>>>(Y0h, mask, GT);

    const long long sAmm = (long long)M * M;
    const long long sFM  = (long long)F * M;
    const long long sMF  = (long long)M * F;

    // t-chunked GCN: A-chunk stays L3-resident between Z1 and Z3 passes;
    // SWAP grid puts the two n-tiles sharing an A-row-panel on the same XCD.
    constexpr int CH = 8;
    for (int c0 = 0; c0 < T; c0 += CH) {
        // Z1 = relu(A_t @ G_t)
        gemm16<true, true, 1,true ><<<dim3(16, 2, CH), 256, 0, stream>>>(
            (const char*)A_all + (size_t)c0 * sAmm * 4, sAmm,
            GT + (size_t)c0 * sFM, sFM, Z1b + (size_t)c0 * sMF, sMF, M, F, M, 0, nullptr);
        // Z2T = (Z1 @ w1)^T
        gemm16<false,false,2,false><<<dim3(2, 16, CH), 256, 0, stream>>>(
            Z1b + (size_t)c0 * sMF, sMF, w1T, 0,
            Z2T + (size_t)c0 * sFM, sFM, F, F, M, M, nullptr);
        // Z3 = relu(A_t @ Z2)   (A_t re-read from L3)
        gemm16<true, true, 1,true ><<<dim3(16, 2, CH), 256, 0, stream>>>(
            (const char*)A_all + (size_t)c0 * sAmm * 4, sAmm,
            Z2T + (size_t)c0 * sFM, sFM, Z3b + (size_t)c0 * sMF, sMF, M, F, M, 0, nullptr);
    }

    // V[t] = Z3_t @ W_ih^T + bias, all 16 steps in one launch
    gemm16<false,false,1,false><<<dim3(G4 / 128, M / 128, T), 256, 0, stream>>>(
        Z3b, sMF, Wih16, 0, Vb, (long long)M * G4, F, G4, M, 0, bsum);

    for (int t = 0; t < T; ++t) {
        gemm_lstm<<<dim3(G4 / 128, NP / 128, 1), 256, 0, stream>>>(
            h16, Whh16, Uh, Vb + (size_t)t * M * G4, inv + (size_t)t * N,
            Cb, h16, (t == T - 1) ? h : nullptr);
    }
}

// Round 6
// 836.957 us; speedup vs baseline: 1.1421x; 1.1421x over previous
//
#include <hip/hip_runtime.h>
#include <cstdint>
#include <cstddef>

#pragma clang diagnostic ignored "-Waddress-space-conversion"

constexpr int T  = 16;
constexpr int N  = 10000;
constexpr int M  = 2048;
constexpr int F  = 256;
constexpr int H  = 256;
constexpr int G4 = 1024;
constexpr int NP = 10112;   // N padded to multiple of 128

typedef _Float16 f16;
using half8  = __attribute__((ext_vector_type(8))) f16;
using half4  = __attribute__((ext_vector_type(4))) f16;
using f32x4  = __attribute__((ext_vector_type(4))) float;

typedef __attribute__((address_space(1))) const void gas_t;
typedef __attribute__((address_space(3))) void las_t;

__device__ __forceinline__ void gl_lds16(const f16* g, f16* l) {
    __builtin_amdgcn_global_load_lds((gas_t*)g, (las_t*)l, 16, 0, 0);
}

// ---------------------------------------------------------------------------
// Generic MFMA GEMM: C[m][n] (+bias[n]) (+relu) = A[m][k] * B[n][k]
// AF32: A is fp32 (reg-staged + converted to f16 LDS); else f16 via global_load_lds.
// OMODE: 1 = f16 row-major, 2 = f16 transposed (C^T [Nn][ldct])
// SWAP:  m-tile on blockIdx.x, n-tile on blockIdx.y (A-panel-sharing blocks land
//        16 apart in dispatch order -> same XCD mod 8, L2/L3 dedup of A fetch)
// 128x128 tile, 4 waves, BK=32, double-buffered LDS. launch_bounds (256,2).
// ---------------------------------------------------------------------------
template<bool AF32, bool RELU, int OMODE, bool SWAP>
__global__ __launch_bounds__(256, 2)
void gemm16(const void* __restrict__ Ag, long long sA,
            const f16*  __restrict__ Bg, long long sB,
            void*       __restrict__ Cg, long long sC,
            int Kk, int Nn, int Mvalid, int ldct,
            const float* __restrict__ bias)
{
    __shared__ f16 Als[2][128 * 32];
    __shared__ f16 Bls[2][128 * 32];

    const int tid  = threadIdx.x;
    const int lane = tid & 63;
    const int w    = tid >> 6;
    const int wm   = w >> 1, wn = w & 1;
    const int m0   = (SWAP ? blockIdx.x : blockIdx.y) * 128;
    const int n0   = (SWAP ? blockIdx.y : blockIdx.x) * 128;
    const int z    = blockIdx.z;

    const f16* Bt = Bg + (size_t)z * sB;
    const int srow = lane >> 2;
    const int scol = (lane & 3) * 8;

    f32x4 acc[4][4] = {};

    auto stage = [&](int buf, int kt) {
        const int k0 = kt * 32;
        #pragma unroll
        for (int c = 0; c < 2; ++c) {
            const int brow = w * 32 + c * 16;
            gl_lds16(Bt + (size_t)(n0 + brow + srow) * Kk + k0 + scol,
                     &Bls[buf][brow * 32]);
        }
        if constexpr (AF32) {
            const float* Af = (const float*)Ag + (size_t)z * sA;
            #pragma unroll
            for (int p = 0; p < 4; ++p) {
                const int flat = p * 1024 + tid * 4;
                const int r = flat >> 5, cc = flat & 31;
                float4 v = *(const float4*)&Af[(size_t)(m0 + r) * Kk + k0 + cc];
                half4 hv = { (f16)v.x, (f16)v.y, (f16)v.z, (f16)v.w };
                *(half4*)&Als[buf][r * 32 + cc] = hv;
            }
        } else {
            const f16* Af = (const f16*)Ag + (size_t)z * sA;
            #pragma unroll
            for (int c = 0; c < 2; ++c) {
                const int arow = w * 32 + c * 16;
                gl_lds16(Af + (size_t)(m0 + arow + srow) * Kk + k0 + scol,
                         &Als[buf][arow * 32]);
            }
        }
    };

    const int nk = Kk >> 5;
    stage(0, 0);
    int cur = 0;
    const int fr = lane & 15, fg = lane >> 4;

    for (int kt = 0; kt < nk; ++kt) {
        __syncthreads();
        if (kt + 1 < nk) stage(cur ^ 1, kt + 1);

        half8 a[4], b[4];
        #pragma unroll
        for (int i = 0; i < 4; ++i)
            a[i] = *(const half8*)&Als[cur][(wm * 64 + i * 16 + fr) * 32 + fg * 8];
        #pragma unroll
        for (int j = 0; j < 4; ++j)
            b[j] = *(const half8*)&Bls[cur][(wn * 64 + j * 16 + fr) * 32 + fg * 8];
        #pragma unroll
        for (int i = 0; i < 4; ++i)
            #pragma unroll
            for (int j = 0; j < 4; ++j)
                acc[i][j] = __builtin_amdgcn_mfma_f32_16x16x32_f16(a[i], b[j], acc[i][j], 0, 0, 0);
        cur ^= 1;
    }

    #pragma unroll
    for (int j = 0; j < 4; ++j) {
        const int gn = n0 + wn * 64 + j * 16 + fr;
        const float bb = bias ? bias[gn] : 0.f;
        #pragma unroll
        for (int i = 0; i < 4; ++i) {
            const int gmb = m0 + wm * 64 + i * 16 + fg * 4;
            f32x4 v = acc[i][j];
            #pragma unroll
            for (int r = 0; r < 4; ++r) {
                v[r] += bb;
                if (RELU) v[r] = fmaxf(v[r], 0.f);
            }
            if constexpr (OMODE == 1) {
                f16* Ch = (f16*)Cg + (size_t)z * sC;
                #pragma unroll
                for (int r = 0; r < 4; ++r)
                    if (gmb + r < Mvalid) Ch[(size_t)(gmb + r) * Nn + gn] = (f16)v[r];
            } else {
                f16* Ct = (f16*)Cg + (size_t)z * sC;
                half4 hv = { (f16)v[0], (f16)v[1], (f16)v[2], (f16)v[3] };
                if (gmb + 3 < Mvalid) *(half4*)&Ct[(size_t)gn * ldct + gmb] = hv;
            }
        }
    }
}

// ---------------------------------------------------------------------------
// Fused recurrent step (bias pre-folded into U/V; c-state in f16).
// Gate-interleaved permuted layout: fragment j == gate j of ONE unit.
// ---------------------------------------------------------------------------
__global__ __launch_bounds__(256, 2)
void gemm_lstm(const f16* __restrict__ h16, const f16* __restrict__ Whh,
               const f16* __restrict__ U, const f16* __restrict__ V,
               const int* __restrict__ invt,
               f16* __restrict__ Cb, f16* __restrict__ h16_out,
               float* __restrict__ hout)
{
    __shared__ f16 Als[2][128 * 32];
    __shared__ f16 Bls[2][128 * 32];

    const int tid  = threadIdx.x;
    const int lane = tid & 63;
    const int w    = tid >> 6;
    const int wm   = w >> 1, wn = w & 1;
    const int m0   = blockIdx.y * 128, n0 = blockIdx.x * 128;

    const int srow = lane >> 2;
    const int scol = (lane & 3) * 8;

    f32x4 acc[4][4] = {};

    auto stage = [&](int buf, int kt) {
        const int k0 = kt * 32;
        #pragma unroll
        for (int c = 0; c < 2; ++c) {
            const int row = w * 32 + c * 16;
            gl_lds16(Whh + (size_t)(n0 + row + srow) * H + k0 + scol, &Bls[buf][row * 32]);
            gl_lds16(h16 + (size_t)(m0 + row + srow) * H + k0 + scol, &Als[buf][row * 32]);
        }
    };

    stage(0, 0);
    int cur = 0;
    const int fr = lane & 15, fg = lane >> 4;

    for (int kt = 0; kt < H / 32; ++kt) {
        __syncthreads();
        if (kt + 1 < H / 32) stage(cur ^ 1, kt + 1);
        half8 a[4], b[4];
        #pragma unroll
        for (int i = 0; i < 4; ++i)
            a[i] = *(const half8*)&Als[cur][(wm * 64 + i * 16 + fr) * 32 + fg * 8];
        #pragma unroll
        for (int j = 0; j < 4; ++j)
            b[j] = *(const half8*)&Bls[cur][(wn * 64 + j * 16 + fr) * 32 + fg * 8];
        #pragma unroll
        for (int i = 0; i < 4; ++i)
            #pragma unroll
            for (int j = 0; j < 4; ++j)
                acc[i][j] = __builtin_amdgcn_mfma_f32_16x16x32_f16(a[i], b[j], acc[i][j], 0, 0, 0);
        cur ^= 1;
    }

    const int u = ((n0 >> 6) + wn) * 16 + fr;
    const int colbase = n0 + wn * 64 + fr;
    auto sig = [](float x) { return 1.f / (1.f + __expf(-x)); };

    #pragma unroll
    for (int i = 0; i < 4; ++i) {
        const int nodeb = m0 + wm * 64 + i * 16 + fg * 4;
        #pragma unroll
        for (int r = 0; r < 4; ++r) {
            const int node = nodeb + r;
            if (node >= N) continue;
            const int p = invt[node];
            const f16* xb = (p >= 0) ? V + (size_t)p * G4 : U + (size_t)node * G4;
            const float zi = acc[i][0][r] + (float)xb[colbase];
            const float zf = acc[i][1][r] + (float)xb[colbase + 16];
            const float zg = acc[i][2][r] + (float)xb[colbase + 32];
            const float zo = acc[i][3][r] + (float)xb[colbase + 48];
            const size_t ci = (size_t)node * H + u;
            const float c = sig(zf) * (float)Cb[ci] + sig(zi) * tanhf(zg);
            Cb[ci] = (f16)c;
            const float hv = sig(zo) * tanhf(c);
            h16_out[ci] = (f16)hv;
            if (hout) hout[ci] = hv;
        }
    }
}

// GT[t][f][p] = Y0h[mask[t][p]][f]
__global__ __launch_bounds__(256)
void gather_T(const f16* __restrict__ Y0h, const int* __restrict__ mask,
              f16* __restrict__ GT)
{
    __shared__ f16 tile[64][F + 8];
    const int t = blockIdx.y, p0 = blockIdx.x * 64;
    const int tid = threadIdx.x;
    const int pr = tid >> 2;
    const int fc = (tid & 3) * 8;

    const int row = mask[t * M + p0 + pr];
    const f16* src = Y0h + (size_t)row * F;
    #pragma unroll
    for (int it = 0; it < 8; ++it) {
        const int f = it * 32 + fc;
        *(half8*)&tile[pr][f] = *(const half8*)&src[f];
    }
    __syncthreads();

    f16* dst = GT + ((size_t)t * F + tid) * M + p0;
    #pragma unroll
    for (int pc = 0; pc < 64; pc += 8) {
        half8 v;
        #pragma unroll
        for (int r = 0; r < 8; ++r) v[r] = tile[pc + r][tid];
        *(half8*)&dst[pc] = v;
    }
}

__global__ void cvt_f16(const float* __restrict__ s, f16* __restrict__ d, long long n)
{
    long long base = ((long long)blockIdx.x * blockDim.x + threadIdx.x) * 4;
    if (base + 3 < n) {
        float4 v = *(const float4*)&s[base];
        half4 hv = { (f16)v.x, (f16)v.y, (f16)v.z, (f16)v.w };
        *(half4*)&d[base] = hv;
    } else {
        for (long long k = base; k < n; ++k) d[k] = (f16)s[k];
    }
}

__global__ void cvtT_f16(const float* __restrict__ s, f16* __restrict__ d, int R, int C)
{
    int i = blockIdx.x * 256 + threadIdx.x;
    if (i >= R * C) return;
    int r = i % R, c = i / R;
    d[(size_t)c * R + r] = (f16)s[(size_t)r * C + c];
}

// Wperm[pcol][k] = W[gate*256 + c64*16 + r][k], pcol = c64*64 + gate*16 + r
__global__ void permW(const float* __restrict__ s, f16* __restrict__ d, int K)
{
    const int pcol = blockIdx.x;
    const int c64 = pcol >> 6, within = pcol & 63, gate = within >> 4, r = within & 15;
    const int srow = gate * 256 + c64 * 16 + r;
    const float* sp = s + (size_t)srow * K;
    f16* dp = d + (size_t)pcol * K;
    const int k = threadIdx.x * 4;
    float4 v = *(const float4*)&sp[k];
    half4 hv = { (f16)v.x, (f16)v.y, (f16)v.z, (f16)v.w };
    *(half4*)&dp[k] = hv;
}

__global__ void bias_perm(const float* __restrict__ bi, const float* __restrict__ bh,
                          float* __restrict__ bsum)
{
    const int pcol = blockIdx.x * 256 + threadIdx.x;
    if (pcol >= G4) return;
    const int c64 = pcol >> 6, within = pcol & 63, gate = within >> 4, r = within & 15;
    const int srow = gate * 256 + c64 * 16 + r;
    bsum[pcol] = bi[srow] + bh[srow];
}

__global__ void build_inv(const int* __restrict__ mask, int* __restrict__ inv)
{
    int i = blockIdx.x * blockDim.x + threadIdx.x;
    if (i >= T * M) return;
    int t = i / M;
    inv[(size_t)t * N + mask[i]] = i % M;
}

extern "C" void kernel_launch(void* const* d_in, const int* in_sizes, int n_in,
                              void* d_out, int out_size, void* d_ws, size_t ws_size,
                              hipStream_t stream)
{
    const float* A_all = (const float*)d_in[0];
    const float* nf    = (const float*)d_in[1];
    const int*   mask  = (const int*)  d_in[2];
    const float* w0    = (const float*)d_in[3];
    const float* w1    = (const float*)d_in[4];
    const float* W_ih  = (const float*)d_in[5];
    const float* W_hh  = (const float*)d_in[6];
    const float* b_ih  = (const float*)d_in[7];
    const float* b_hh  = (const float*)d_in[8];
    float* h = (float*)d_out;

    char* wp = (char*)d_ws;
    auto alloc = [&](size_t bytes) { char* p = wp; wp += (bytes + 255) & ~(size_t)255; return p; };
    f16*   nf16  = (f16*)alloc((size_t)NP * F * 2);
    f16*   w0T   = (f16*)alloc((size_t)F * F * 2);
    f16*   w1T   = (f16*)alloc((size_t)F * F * 2);
    f16*   Wih16 = (f16*)alloc((size_t)G4 * F * 2);   // permuted rows
    f16*   Whh16 = (f16*)alloc((size_t)G4 * H * 2);   // permuted rows
    float* bsum  = (float*)alloc((size_t)G4 * 4);
    f16*   Y0h   = (f16*)alloc((size_t)NP * F * 2);
    f16*   Y1h   = (f16*)alloc((size_t)NP * F * 2);
    f16*   Uh    = (f16*)alloc((size_t)NP * G4 * 2);  // permuted cols, bias folded
    f16*   GT    = (f16*)alloc((size_t)T * F * M * 2);
    f16*   Z1b   = (f16*)alloc((size_t)T * M * F * 2);
    f16*   Z2T   = (f16*)alloc((size_t)T * F * M * 2);
    f16*   Z3b   = (f16*)alloc((size_t)T * M * F * 2);
    f16*   Vb    = (f16*)alloc((size_t)T * M * G4 * 2);  // all 16 steps
    f16*   Cb    = (f16*)alloc((size_t)N * H * 2);
    f16*   h16   = (f16*)alloc((size_t)NP * H * 2);
    int*   inv   = (int*)alloc((size_t)T * N * 4);

    hipMemsetAsync(Cb,  0,    (size_t)N * H * 2,  stream);
    hipMemsetAsync(h16, 0,    (size_t)NP * H * 2, stream);
    hipMemsetAsync(nf16,0,    (size_t)NP * F * 2, stream);
    hipMemsetAsync(inv, 0xFF, (size_t)T * N * 4,  stream);

    build_inv<<<(T * M + 255) / 256, 256, 0, stream>>>(mask, inv);
    cvt_f16 <<<((long long)N * F / 4 + 255) / 256, 256, 0, stream>>>(nf, nf16, (long long)N * F);
    cvtT_f16<<<(F * F + 255) / 256, 256, 0, stream>>>(w0, w0T, F, F);
    cvtT_f16<<<(F * F + 255) / 256, 256, 0, stream>>>(w1, w1T, F, F);
    permW<<<G4, 64, 0, stream>>>(W_ih, Wih16, F);
    permW<<<G4, 64, 0, stream>>>(W_hh, Whh16, H);
    bias_perm<<<(G4 + 255) / 256, 256, 0, stream>>>(b_ih, b_hh, bsum);

    gemm16<false,false,1,false><<<dim3(F / 128,  NP / 128, 1), 256, 0, stream>>>(nf16, 0, w0T,   0, Y0h, 0, F, F,  NP, 0, nullptr);
    gemm16<false,false,1,false><<<dim3(F / 128,  NP / 128, 1), 256, 0, stream>>>(Y0h,  0, w1T,   0, Y1h, 0, F, F,  NP, 0, nullptr);
    gemm16<false,false,1,false><<<dim3(G4 / 128, NP / 128, 1), 256, 0, stream>>>(Y1h,  0, Wih16, 0, Uh,  0, F, G4, NP, 0, bsum);

    gather_T<<<dim3(M / 64, T), 256, 0, stream>>>(Y0h, mask, GT);

    const long long sAmm = (long long)M * M;
    const long long sFM  = (long long)F * M;
    const long long sMF  = (long long)M * F;

    // Z1 = relu(A_t @ G_t)  : SWAP grid for A-panel L2/L3 dedup
    gemm16<true, true, 1,true ><<<dim3(16, 2, T), 256, 0, stream>>>(
        A_all, sAmm, GT, sFM, Z1b, sMF, M, F, M, 0, nullptr);
    // Z2T = (Z1 @ w1)^T
    gemm16<false,false,2,false><<<dim3(2, 16, T), 256, 0, stream>>>(
        Z1b, sMF, w1T, 0, Z2T, sFM, F, F, M, M, nullptr);
    // Z3 = relu(A_t @ Z2)   : SWAP grid
    gemm16<true, true, 1,true ><<<dim3(16, 2, T), 256, 0, stream>>>(
        A_all, sAmm, Z2T, sFM, Z3b, sMF, M, F, M, 0, nullptr);

    // V[t] = Z3_t @ W_ih^T + bias, all 16 steps in one launch
    gemm16<false,false,1,false><<<dim3(G4 / 128, M / 128, T), 256, 0, stream>>>(
        Z3b, sMF, Wih16, 0, Vb, (long long)M * G4, F, G4, M, 0, bsum);

    for (int t = 0; t < T; ++t) {
        gemm_lstm<<<dim3(G4 / 128, NP / 128, 1), 256, 0, stream>>>(
            h16, Whh16, Uh, Vb + (size_t)t * M * G4, inv + (size_t)t * N,
            Cb, h16, (t == T - 1) ? h : nullptr);
    }
}

// Round 7
// 765.626 us; speedup vs baseline: 1.2485x; 1.0932x over previous
//
#include <hip/hip_runtime.h>
#include <cstdint>
#include <cstddef>

#pragma clang diagnostic ignored "-Waddress-space-conversion"

constexpr int T  = 16;
constexpr int N  = 10000;
constexpr int M  = 2048;
constexpr int F  = 256;
constexpr int H  = 256;
constexpr int G4 = 1024;
constexpr int NP = 10112;   // N padded to multiple of 128

typedef _Float16 f16;
using half8  = __attribute__((ext_vector_type(8))) f16;
using half4  = __attribute__((ext_vector_type(4))) f16;
using f32x4  = __attribute__((ext_vector_type(4))) float;

typedef __attribute__((address_space(1))) const void gas_t;
typedef __attribute__((address_space(3))) void las_t;

__device__ __forceinline__ void gl_lds16(const f16* g, f16* l) {
    __builtin_amdgcn_global_load_lds((gas_t*)g, (las_t*)l, 16, 0, 0);
}

__device__ __forceinline__ float fast_tanh(float x) {
    // tanh(x) = sign(x) * (1 - e) / (1 + e), e = exp(-2|x|); HW v_exp_f32
    const float ax = fabsf(x);
    const float e  = __expf(-2.f * ax);
    const float t  = (1.f - e) / (1.f + e);
    return copysignf(t, x);
}

// ---------------------------------------------------------------------------
// Generic MFMA GEMM: C[m][n] (+relu) = A[m][k] * B[n][k]  (k-contiguous operands)
// AF32: A fp32 (reg-staged + converted); else f16 via global_load_lds.
// OMODE: 1 = f16 row-major, 2 = f16 transposed (C^T [Nn][ldct])
// 128x128 tile, 4 waves, BK=32, double-buffered LDS. (round-3 structure)
// ---------------------------------------------------------------------------
template<bool AF32, bool RELU, int OMODE>
__global__ __launch_bounds__(256, 2)
void gemm16(const void* __restrict__ Ag, long long sA,
            const f16*  __restrict__ Bg, long long sB,
            void*       __restrict__ Cg, long long sC,
            int Kk, int Nn, int Mvalid, int ldct)
{
    __shared__ f16 Als[2][128 * 32];
    __shared__ f16 Bls[2][128 * 32];

    const int tid  = threadIdx.x;
    const int lane = tid & 63;
    const int w    = tid >> 6;
    const int wm   = w >> 1, wn = w & 1;
    const int m0   = blockIdx.y * 128, n0 = blockIdx.x * 128;
    const int z    = blockIdx.z;

    const f16* Bt = Bg + (size_t)z * sB;
    const int srow = lane >> 2;
    const int scol = (lane & 3) * 8;

    f32x4 acc[4][4] = {};

    auto stage = [&](int buf, int kt) {
        const int k0 = kt * 32;
        #pragma unroll
        for (int c = 0; c < 2; ++c) {
            const int brow = w * 32 + c * 16;
            gl_lds16(Bt + (size_t)(n0 + brow + srow) * Kk + k0 + scol,
                     &Bls[buf][brow * 32]);
        }
        if constexpr (AF32) {
            const float* Af = (const float*)Ag + (size_t)z * sA;
            #pragma unroll
            for (int p = 0; p < 4; ++p) {
                const int flat = p * 1024 + tid * 4;
                const int r = flat >> 5, cc = flat & 31;
                float4 v = *(const float4*)&Af[(size_t)(m0 + r) * Kk + k0 + cc];
                half4 hv = { (f16)v.x, (f16)v.y, (f16)v.z, (f16)v.w };
                *(half4*)&Als[buf][r * 32 + cc] = hv;
            }
        } else {
            const f16* Af = (const f16*)Ag + (size_t)z * sA;
            #pragma unroll
            for (int c = 0; c < 2; ++c) {
                const int arow = w * 32 + c * 16;
                gl_lds16(Af + (size_t)(m0 + arow + srow) * Kk + k0 + scol,
                         &Als[buf][arow * 32]);
            }
        }
    };

    const int nk = Kk >> 5;
    stage(0, 0);
    int cur = 0;
    const int fr = lane & 15, fg = lane >> 4;

    for (int kt = 0; kt < nk; ++kt) {
        __syncthreads();
        if (kt + 1 < nk) stage(cur ^ 1, kt + 1);

        half8 a[4], b[4];
        #pragma unroll
        for (int i = 0; i < 4; ++i)
            a[i] = *(const half8*)&Als[cur][(wm * 64 + i * 16 + fr) * 32 + fg * 8];
        #pragma unroll
        for (int j = 0; j < 4; ++j)
            b[j] = *(const half8*)&Bls[cur][(wn * 64 + j * 16 + fr) * 32 + fg * 8];
        #pragma unroll
        for (int i = 0; i < 4; ++i)
            #pragma unroll
            for (int j = 0; j < 4; ++j)
                acc[i][j] = __builtin_amdgcn_mfma_f32_16x16x32_f16(a[i], b[j], acc[i][j], 0, 0, 0);
        cur ^= 1;
    }

    #pragma unroll
    for (int i = 0; i < 4; ++i) {
        const int gmb = m0 + wm * 64 + i * 16 + fg * 4;
        #pragma unroll
        for (int j = 0; j < 4; ++j) {
            const int gn = n0 + wn * 64 + j * 16 + fr;
            f32x4 v = acc[i][j];
            if (RELU) {
                v[0] = fmaxf(v[0], 0.f); v[1] = fmaxf(v[1], 0.f);
                v[2] = fmaxf(v[2], 0.f); v[3] = fmaxf(v[3], 0.f);
            }
            if constexpr (OMODE == 1) {
                f16* Ch = (f16*)Cg + (size_t)z * sC;
                #pragma unroll
                for (int r = 0; r < 4; ++r)
                    if (gmb + r < Mvalid) Ch[(size_t)(gmb + r) * Nn + gn] = (f16)v[r];
            } else {
                f16* Ct = (f16*)Cg + (size_t)z * sC;
                half4 hv = { (f16)v[0], (f16)v[1], (f16)v[2], (f16)v[3] };
                if (gmb + 3 < Mvalid) *(half4*)&Ct[(size_t)gn * ldct + gmb] = hv;
            }
        }
    }
}

// ---------------------------------------------------------------------------
// Fused recurrent step (round-3 structure: f32 Cb, bsum in epilogue),
// fast_tanh replacing tanhf.
// ---------------------------------------------------------------------------
__global__ __launch_bounds__(256, 2)
void gemm_lstm(const f16* __restrict__ h16, const f16* __restrict__ Whh,
               const f16* __restrict__ U, const f16* __restrict__ V,
               const int* __restrict__ invt, const float* __restrict__ bsum,
               float* __restrict__ Cb, f16* __restrict__ h16_out,
               float* __restrict__ hout)
{
    __shared__ f16 Als[2][128 * 32];
    __shared__ f16 Bls[2][128 * 32];

    const int tid  = threadIdx.x;
    const int lane = tid & 63;
    const int w    = tid >> 6;
    const int wm   = w >> 1, wn = w & 1;
    const int m0   = blockIdx.y * 128, n0 = blockIdx.x * 128;

    const int srow = lane >> 2;
    const int scol = (lane & 3) * 8;

    f32x4 acc[4][4] = {};

    auto stage = [&](int buf, int kt) {
        const int k0 = kt * 32;
        #pragma unroll
        for (int c = 0; c < 2; ++c) {
            const int row = w * 32 + c * 16;
            gl_lds16(Whh + (size_t)(n0 + row + srow) * H + k0 + scol, &Bls[buf][row * 32]);
            gl_lds16(h16 + (size_t)(m0 + row + srow) * H + k0 + scol, &Als[buf][row * 32]);
        }
    };

    stage(0, 0);
    int cur = 0;
    const int fr = lane & 15, fg = lane >> 4;

    for (int kt = 0; kt < H / 32; ++kt) {
        __syncthreads();
        if (kt + 1 < H / 32) stage(cur ^ 1, kt + 1);
        half8 a[4], b[4];
        #pragma unroll
        for (int i = 0; i < 4; ++i)
            a[i] = *(const half8*)&Als[cur][(wm * 64 + i * 16 + fr) * 32 + fg * 8];
        #pragma unroll
        for (int j = 0; j < 4; ++j)
            b[j] = *(const half8*)&Bls[cur][(wn * 64 + j * 16 + fr) * 32 + fg * 8];
        #pragma unroll
        for (int i = 0; i < 4; ++i)
            #pragma unroll
            for (int j = 0; j < 4; ++j)
                acc[i][j] = __builtin_amdgcn_mfma_f32_16x16x32_f16(a[i], b[j], acc[i][j], 0, 0, 0);
        cur ^= 1;
    }

    const int u = ((n0 >> 6) + wn) * 16 + fr;
    const int colbase = n0 + wn * 64 + fr;
    const float b0 = bsum[colbase], b1 = bsum[colbase + 16],
                b2 = bsum[colbase + 32], b3 = bsum[colbase + 48];
    auto sig = [](float x) { return 1.f / (1.f + __expf(-x)); };

    #pragma unroll
    for (int i = 0; i < 4; ++i) {
        const int nodeb = m0 + wm * 64 + i * 16 + fg * 4;
        #pragma unroll
        for (int r = 0; r < 4; ++r) {
            const int node = nodeb + r;
            if (node >= N) continue;
            const int p = invt[node];
            const f16* xb = (p >= 0) ? V + (size_t)p * G4 : U + (size_t)node * G4;
            const float zi = acc[i][0][r] + (float)xb[colbase]      + b0;
            const float zf = acc[i][1][r] + (float)xb[colbase + 16] + b1;
            const float zg = acc[i][2][r] + (float)xb[colbase + 32] + b2;
            const float zo = acc[i][3][r] + (float)xb[colbase + 48] + b3;
            const size_t ci = (size_t)node * H + u;
            const float c = sig(zf) * Cb[ci] + sig(zi) * fast_tanh(zg);
            Cb[ci] = c;
            const float hv = sig(zo) * fast_tanh(c);
            h16_out[ci] = (f16)hv;
            if (hout) hout[ci] = hv;
        }
    }
}

// GT[t][f][p] = Y0h[mask[t][p]][f]
__global__ __launch_bounds__(256)
void gather_T(const f16* __restrict__ Y0h, const int* __restrict__ mask,
              f16* __restrict__ GT)
{
    __shared__ f16 tile[64][F + 8];
    const int t = blockIdx.y, p0 = blockIdx.x * 64;
    const int tid = threadIdx.x;
    const int pr = tid >> 2;
    const int fc = (tid & 3) * 8;

    const int row = mask[t * M + p0 + pr];
    const f16* src = Y0h + (size_t)row * F;
    #pragma unroll
    for (int it = 0; it < 8; ++it) {
        const int f = it * 32 + fc;
        *(half8*)&tile[pr][f] = *(const half8*)&src[f];
    }
    __syncthreads();

    f16* dst = GT + ((size_t)t * F + tid) * M + p0;
    #pragma unroll
    for (int pc = 0; pc < 64; pc += 8) {
        half8 v;
        #pragma unroll
        for (int r = 0; r < 8; ++r) v[r] = tile[pc + r][tid];
        *(half8*)&dst[pc] = v;
    }
}

__global__ void cvt_f16(const float* __restrict__ s, f16* __restrict__ d, long long n)
{
    long long base = ((long long)blockIdx.x * blockDim.x + threadIdx.x) * 4;
    if (base + 3 < n) {
        float4 v = *(const float4*)&s[base];
        half4 hv = { (f16)v.x, (f16)v.y, (f16)v.z, (f16)v.w };
        *(half4*)&d[base] = hv;
    } else {
        for (long long k = base; k < n; ++k) d[k] = (f16)s[k];
    }
}

__global__ void cvtT_f16(const float* __restrict__ s, f16* __restrict__ d, int R, int C)
{
    int i = blockIdx.x * 256 + threadIdx.x;
    if (i >= R * C) return;
    int r = i % R, c = i / R;
    d[(size_t)c * R + r] = (f16)s[(size_t)r * C + c];
}

// Wperm[pcol][k] = W[gate*256 + c64*16 + r][k], pcol = c64*64 + gate*16 + r
__global__ void permW(const float* __restrict__ s, f16* __restrict__ d, int K)
{
    const int pcol = blockIdx.x;
    const int c64 = pcol >> 6, within = pcol & 63, gate = within >> 4, r = within & 15;
    const int srow = gate * 256 + c64 * 16 + r;
    const float* sp = s + (size_t)srow * K;
    f16* dp = d + (size_t)pcol * K;
    const int k = threadIdx.x * 4;
    float4 v = *(const float4*)&sp[k];
    half4 hv = { (f16)v.x, (f16)v.y, (f16)v.z, (f16)v.w };
    *(half4*)&dp[k] = hv;
}

__global__ void bias_perm(const float* __restrict__ bi, const float* __restrict__ bh,
                          float* __restrict__ bsum)
{
    const int pcol = blockIdx.x * 256 + threadIdx.x;
    if (pcol >= G4) return;
    const int c64 = pcol >> 6, within = pcol & 63, gate = within >> 4, r = within & 15;
    const int srow = gate * 256 + c64 * 16 + r;
    bsum[pcol] = bi[srow] + bh[srow];
}

__global__ void build_inv(const int* __restrict__ mask, int* __restrict__ inv)
{
    int i = blockIdx.x * blockDim.x + threadIdx.x;
    if (i >= T * M) return;
    int t = i / M;
    inv[(size_t)t * N + mask[i]] = i % M;
}

extern "C" void kernel_launch(void* const* d_in, const int* in_sizes, int n_in,
                              void* d_out, int out_size, void* d_ws, size_t ws_size,
                              hipStream_t stream)
{
    const float* A_all = (const float*)d_in[0];
    const float* nf    = (const float*)d_in[1];
    const int*   mask  = (const int*)  d_in[2];
    const float* w0    = (const float*)d_in[3];
    const float* w1    = (const float*)d_in[4];
    const float* W_ih  = (const float*)d_in[5];
    const float* W_hh  = (const float*)d_in[6];
    const float* b_ih  = (const float*)d_in[7];
    const float* b_hh  = (const float*)d_in[8];
    float* h = (float*)d_out;

    char* wp = (char*)d_ws;
    auto alloc = [&](size_t bytes) { char* p = wp; wp += (bytes + 255) & ~(size_t)255; return p; };
    f16*   nf16  = (f16*)alloc((size_t)NP * F * 2);
    f16*   w0T   = (f16*)alloc((size_t)F * F * 2);
    f16*   w1T   = (f16*)alloc((size_t)F * F * 2);
    f16*   Wih16 = (f16*)alloc((size_t)G4 * F * 2);   // permuted rows
    f16*   Whh16 = (f16*)alloc((size_t)G4 * H * 2);   // permuted rows
    float* bsum  = (float*)alloc((size_t)G4 * 4);
    f16*   Y0h   = (f16*)alloc((size_t)NP * F * 2);
    f16*   Y1h   = (f16*)alloc((size_t)NP * F * 2);
    f16*   Uh    = (f16*)alloc((size_t)NP * G4 * 2);  // permuted cols
    f16*   GT    = (f16*)alloc((size_t)T * F * M * 2);
    f16*   Z1b   = (f16*)alloc((size_t)T * M * F * 2);
    f16*   Z2T   = (f16*)alloc((size_t)T * F * M * 2);
    f16*   Z3b   = (f16*)alloc((size_t)T * M * F * 2);
    f16*   Vb    = (f16*)alloc((size_t)4 * M * G4 * 2);   // 4-step chunks
    float* Cb    = (float*)alloc((size_t)N * H * 4);      // f32 cell state (round-3)
    f16*   h16   = (f16*)alloc((size_t)NP * H * 2);
    int*   inv   = (int*)alloc((size_t)T * N * 4);

    // A16 is optional (needs +134 MB scratch); deterministic ws_size guard.
    const size_t a16_bytes = (size_t)T * M * M * 2;
    const size_t used      = (size_t)(wp - (char*)d_ws);
    const bool   useA16    = (used + a16_bytes) <= ws_size;
    f16* A16 = useA16 ? (f16*)alloc(a16_bytes) : nullptr;

    hipMemsetAsync(Cb,  0,    (size_t)N * H * 4,  stream);
    hipMemsetAsync(h16, 0,    (size_t)NP * H * 2, stream);
    hipMemsetAsync(nf16,0,    (size_t)NP * F * 2, stream);
    hipMemsetAsync(inv, 0xFF, (size_t)T * N * 4,  stream);

    build_inv<<<(T * M + 255) / 256, 256, 0, stream>>>(mask, inv);
    cvt_f16 <<<((long long)N * F / 4 + 255) / 256, 256, 0, stream>>>(nf, nf16, (long long)N * F);
    cvtT_f16<<<(F * F + 255) / 256, 256, 0, stream>>>(w0, w0T, F, F);
    cvtT_f16<<<(F * F + 255) / 256, 256, 0, stream>>>(w1, w1T, F, F);
    permW<<<G4, 64, 0, stream>>>(W_ih, Wih16, F);
    permW<<<G4, 64, 0, stream>>>(W_hh, Whh16, H);
    bias_perm<<<(G4 + 255) / 256, 256, 0, stream>>>(b_ih, b_hh, bsum);

    gemm16<false,false,1><<<dim3(F / 128,  NP / 128, 1), 256, 0, stream>>>(nf16, 0, w0T,   0, Y0h, 0, F, F,  NP, 0);
    gemm16<false,false,1><<<dim3(F / 128,  NP / 128, 1), 256, 0, stream>>>(Y0h,  0, w1T,   0, Y1h, 0, F, F,  NP, 0);
    gemm16<false,false,1><<<dim3(G4 / 128, NP / 128, 1), 256, 0, stream>>>(Y1h,  0, Wih16, 0, Uh,  0, F, G4, NP, 0);

    gather_T<<<dim3(M / 64, T), 256, 0, stream>>>(Y0h, mask, GT);

    const long long sAmm = (long long)M * M;
    const long long sFM  = (long long)F * M;
    const long long sMF  = (long long)M * F;

    if (useA16) {
        // one-time fp32->f16 of A (134 MB, L3-resident for both passes)
        cvt_f16<<<(int)(((long long)T * M * M / 4 + 255) / 256), 256, 0, stream>>>(
            A_all, A16, (long long)T * M * M);
        gemm16<false,true, 1><<<dim3(2, 16, T), 256, 0, stream>>>(A16, sAmm, GT,  sFM, Z1b, sMF, M, F, M, 0);
        gemm16<false,false,2><<<dim3(2, 16, T), 256, 0, stream>>>(Z1b, sMF,  w1T, 0,   Z2T, sFM, F, F, M, M);
        gemm16<false,true, 1><<<dim3(2, 16, T), 256, 0, stream>>>(A16, sAmm, Z2T, sFM, Z3b, sMF, M, F, M, 0);
    } else {
        gemm16<true, true, 1><<<dim3(2, 16, T), 256, 0, stream>>>(A_all, sAmm, GT,  sFM, Z1b, sMF, M, F, M, 0);
        gemm16<false,false,2><<<dim3(2, 16, T), 256, 0, stream>>>(Z1b,  sMF,  w1T, 0,   Z2T, sFM, F, F, M, M);
        gemm16<true, true, 1><<<dim3(2, 16, T), 256, 0, stream>>>(A_all, sAmm, Z2T, sFM, Z3b, sMF, M, F, M, 0);
    }

    for (int t = 0; t < T; ++t) {
        if ((t & 3) == 0) {  // V[t..t+3] = Z3 @ W_ih^T (4-step batch, round-3 shape)
            gemm16<false,false,1><<<dim3(G4 / 128, M / 128, 4), 256, 0, stream>>>(
                Z3b + (size_t)t * M * F, sMF, Wih16, 0, Vb, (long long)M * G4, F, G4, M, 0);
        }
        gemm_lstm<<<dim3(G4 / 128, NP / 128, 1), 256, 0, stream>>>(
            h16, Whh16, Uh, Vb + (size_t)(t & 3) * M * G4, inv + (size_t)t * N,
            bsum, Cb, h16, (t == T - 1) ? h : nullptr);
    }
}